// Round 8
// baseline (194.899 us; speedup 1.0000x reference)
//
#include <hip/hip_runtime.h>

// B=64, L=512, D=768, V=100
// summed[b,l,:] = w0s * pooler[b,l,:] + w1s * xt[b,:]
//   xt[b,d] = e0*W[0,d] + e1*W[1,d] + b_dense[d],  (e0,e1) = emb_table[ids[b]]
//   s00 = p.p (row), s01 = p.xt (row), s11 = xt.xt (per b); S0 = sum p, S1 = sum xt
//   out = gamma*(a*p + (c*xt - m)) + beta,  a=w0s*rstd, c=w1s*rstd, m=mean*rstd
//
// History (kernel time):
// R0 1-row/wave + NT:            <58.4us  (tied best)
// R3 4-row serialized:            ~65us
// R4/R5 loads-up-front (+LB):     ~62us   compiler sank/remat'd the tile
// R6 two-pass:                    ~71us   +66% traffic
// R7 LDS stash, no barrier:      <58.4us  (tied best)
// R8 plain stores vs NT:          ~63us   store path exonerated
// R9 "skewed" 8-row stream:       ~63us   VGPR=44: load and use were in the
//    SAME static iteration (epilogue between = ~50cyc, not 900) — no skew.
// R10: true MODULO SCHEDULE: consume buffer A (row r) at iteration top,
//    refill A with row r+2's loads mid-iteration. Load and use live in
//    DIFFERENT iterations -> sinking across the backedge is impossible;
//    compiler's counted waitcnt gives vmcnt(3) (never 0) in steady state.
//    Tile reuse via R7's barrier-free per-wave LDS slots (no register tile
//    across the butterfly -> no remat pathology). 1024 blocks, 16 waves/CU,
//    each wave streams 8 rows with ~2 row-phases of load->use distance.

constexpr int Bc = 64;
constexpr int Lc = 512;
constexpr int Dc = 768;            // 192 float4 = 3 float4 per lane (wave64)
constexpr int NF4 = Dc / 4;        // 192
constexpr float LN_EPS = 1e-6f;
constexpr int WPB = 4;             // waves per block
constexpr int RPW = 8;             // rows streamed per wave (8 | 512 -> one b)
constexpr int RPB = WPB * RPW;     // 32 rows per block

typedef float nv_float4 __attribute__((ext_vector_type(4)));

__global__ __launch_bounds__(64 * WPB, 4) void hier_attn_ln_kernel(
    const int*   __restrict__ ids,        // (B,1)
    const float* __restrict__ pooler,     // (B,L,D)
    const float* __restrict__ emb_table,  // (V,2)
    const float* __restrict__ W,          // (2,D)
    const float* __restrict__ bvec,       // (D,)
    const float* __restrict__ gamma,      // (D,)
    const float* __restrict__ beta,       // (D,)
    float*       __restrict__ out)        // (B,L,D)
{
    // Per-wave double-buffer slots; same-wave write->read is program-ordered
    // on lgkmcnt -> no __syncthreads anywhere.
    __shared__ float4 tile[WPB][2][NF4];            // 4*2*192*16 B = 24 KB

    const int wave = threadIdx.x >> 6;
    const int lane = threadIdx.x & 63;
    const int wid  = blockIdx.x * WPB + wave;       // 0..4095
    const int row0 = wid * RPW;                     // 8 consecutive rows
    const int b    = row0 >> 9;                     // L=512; 8|512 -> one b

    const float4* W0_4 = (const float4*)W;
    const float4* W1_4 = (const float4*)(W + Dc);
    const float4* b_4  = (const float4*)bvec;
    const float4* g_4  = (const float4*)gamma;
    const float4* be_4 = (const float4*)beta;

    const int id = ids[b];
    const float e0 = emb_table[id * 2 + 0];
    const float e1 = emb_table[id * 2 + 1];

    // ---- loop invariants: xt, gamma, beta + per-b reduced s11/S1 ----
    float4 xt[3], gm[3], bt[3];
    float s11 = 0.f, S1 = 0.f;
#pragma unroll
    for (int j = 0; j < 3; ++j) {
        const int i4 = lane + j * 64;
        float4 w0 = W0_4[i4], w1 = W1_4[i4], bd = b_4[i4];
        gm[j] = g_4[i4];
        bt[j] = be_4[i4];
        float4 x;
        x.x = fmaf(e0, w0.x, fmaf(e1, w1.x, bd.x));
        x.y = fmaf(e0, w0.y, fmaf(e1, w1.y, bd.y));
        x.z = fmaf(e0, w0.z, fmaf(e1, w1.z, bd.z));
        x.w = fmaf(e0, w0.w, fmaf(e1, w1.w, bd.w));
        xt[j] = x;
        s11 += x.x*x.x + x.y*x.y + x.z*x.z + x.w*x.w;
        S1  += x.x + x.y + x.z + x.w;
    }
#pragma unroll
    for (int off = 32; off > 0; off >>= 1) {
        s11 += __shfl_xor(s11, off);
        S1  += __shfl_xor(S1,  off);
    }

    const float invD = 1.f / (float)Dc;
    const float4* p_base = (const float4*)(pooler + (size_t)row0 * Dc);
    nv_float4*    o_base = (nv_float4*)(out + (size_t)row0 * Dc);

    // consume: partial sums + stash to own LDS slot (loaded value dies here)
#define CONSUME(Q0, Q1, Q2, SLOT, A0, A1, A2)                                   \
    do {                                                                        \
        A0  = Q0.x*Q0.x + Q0.y*Q0.y + Q0.z*Q0.z + Q0.w*Q0.w;                    \
        A1  = Q0.x*xt[0].x + Q0.y*xt[0].y + Q0.z*xt[0].z + Q0.w*xt[0].w;        \
        A2  = Q0.x + Q0.y + Q0.z + Q0.w;                                        \
        A0 += Q1.x*Q1.x + Q1.y*Q1.y + Q1.z*Q1.z + Q1.w*Q1.w;                    \
        A1 += Q1.x*xt[1].x + Q1.y*xt[1].y + Q1.z*xt[1].z + Q1.w*xt[1].w;        \
        A2 += Q1.x + Q1.y + Q1.z + Q1.w;                                        \
        A0 += Q2.x*Q2.x + Q2.y*Q2.y + Q2.z*Q2.z + Q2.w*Q2.w;                    \
        A1 += Q2.x*xt[2].x + Q2.y*xt[2].y + Q2.z*xt[2].z + Q2.w*xt[2].w;        \
        A2 += Q2.x + Q2.y + Q2.z + Q2.w;                                        \
        tile[wave][SLOT][lane]       = Q0;                                      \
        tile[wave][SLOT][lane + 64]  = Q1;                                      \
        tile[wave][SLOT][lane + 128] = Q2;                                      \
    } while (0)

    // finish: butterfly -> softmax -> LN scalars -> LDS re-read -> NT store
#define FINISH(SLOT, R, A0, A1, A2)                                             \
    do {                                                                        \
        _Pragma("unroll")                                                       \
        for (int off = 32; off > 0; off >>= 1) {                                \
            A0 += __shfl_xor(A0, off);                                          \
            A1 += __shfl_xor(A1, off);                                          \
            A2 += __shfl_xor(A2, off);                                          \
        }                                                                       \
        const float m0  = fmaxf(A0, A1);                                        \
        const float x00 = __expf(A0 - m0);                                      \
        const float x01 = __expf(A1 - m0);                                      \
        const float r0_ = 1.f / (x00 + x01);                                    \
        const float m1  = fmaxf(A1, s11);                                       \
        const float x10 = __expf(A1 - m1);                                      \
        const float x11 = __expf(s11 - m1);                                     \
        const float r1_ = 1.f / (x10 + x11);                                    \
        const float w0s = x00 * r0_ + x10 * r1_;                                \
        const float w1s = x01 * r0_ + x11 * r1_;                                \
        const float mean = (w0s * A2 + w1s * S1) * invD;                        \
        const float ex2  = (w0s*w0s*A0 + 2.f*w0s*w1s*A1 + w1s*w1s*s11) * invD;  \
        const float rstd = rsqrtf(ex2 - mean * mean + LN_EPS);                  \
        const float pa = w0s * rstd, pc = w1s * rstd, pm = mean * rstd;         \
        nv_float4* orow = o_base + (size_t)(R) * NF4;                           \
        _Pragma("unroll")                                                       \
        for (int j = 0; j < 3; ++j) {                                           \
            const float4 p = tile[wave][SLOT][lane + j * 64];                   \
            nv_float4 o;                                                        \
            o.x = fmaf(gm[j].x, fmaf(pa, p.x, fmaf(pc, xt[j].x, -pm)), bt[j].x);\
            o.y = fmaf(gm[j].y, fmaf(pa, p.y, fmaf(pc, xt[j].y, -pm)), bt[j].y);\
            o.z = fmaf(gm[j].z, fmaf(pa, p.z, fmaf(pc, xt[j].z, -pm)), bt[j].z);\
            o.w = fmaf(gm[j].w, fmaf(pa, p.w, fmaf(pc, xt[j].w, -pm)), bt[j].w);\
            __builtin_nontemporal_store(o, &orow[lane + j * 64]);               \
        }                                                                       \
    } while (0)

    // ---- prologue: fill both buffers (rows 0 and 1) ----
    float4 qa0 = p_base[lane],        qa1 = p_base[lane + 64],
           qa2 = p_base[lane + 128];
    float4 qb0 = p_base[NF4 + lane],  qb1 = p_base[NF4 + lane + 64],
           qb2 = p_base[NF4 + lane + 128];

    // ---- modulo-scheduled steady state: consume row r, refill with r+2 ----
#pragma unroll 1
    for (int it = 0; it < RPW / 2; ++it) {
        const int r0 = 2 * it;
        const bool more = (it < RPW / 2 - 1);
        float a0, a1, a2;

        // row r0: consume A, refill A with row r0+2 (used NEXT iteration)
        CONSUME(qa0, qa1, qa2, 0, a0, a1, a2);
        if (more) {
            const float4* nb = p_base + (size_t)(r0 + 2) * NF4;
            qa0 = nb[lane]; qa1 = nb[lane + 64]; qa2 = nb[lane + 128];
        }
        FINISH(0, r0, a0, a1, a2);

        // row r0+1: consume B, refill B with row r0+3
        CONSUME(qb0, qb1, qb2, 1, a0, a1, a2);
        if (more) {
            const float4* nb = p_base + (size_t)(r0 + 3) * NF4;
            qb0 = nb[lane]; qb1 = nb[lane + 64]; qb2 = nb[lane + 128];
        }
        FINISH(1, r0 + 1, a0, a1, a2);
    }
#undef CONSUME
#undef FINISH
}

extern "C" void kernel_launch(void* const* d_in, const int* in_sizes, int n_in,
                              void* d_out, int out_size, void* d_ws, size_t ws_size,
                              hipStream_t stream) {
    const int*   ids       = (const int*)  d_in[0];
    const float* pooler    = (const float*)d_in[1];
    const float* emb_table = (const float*)d_in[2];
    const float* W_dense   = (const float*)d_in[3];
    const float* b_dense   = (const float*)d_in[4];
    const float* gamma     = (const float*)d_in[5];
    const float* beta      = (const float*)d_in[6];
    float* out = (float*)d_out;

    const int nrows = Bc * Lc;                      // 32768
    hipLaunchKernelGGL(hier_attn_ln_kernel,
                       dim3(nrows / RPB), dim3(64 * WPB),   // 1024 blocks
                       0, stream,
                       ids, pooler, emb_table, W_dense, b_dense, gamma, beta, out);
}